// Round 3
// baseline (595.955 us; speedup 1.0000x reference)
//
#include <hip/hip_runtime.h>
#include <hip/hip_cooperative_groups.h>
#include <math.h>

namespace cg = cooperative_groups;

#define N_V   8192
#define N_E   4096
#define V_HID 128
#define H0_   64
#define CAP   96      // row nz capacity  (mean 41, sigma 6.4)
#define CAPC  144     // col nz capacity  (mean 82, sigma 9.0)
#define BN_EPS 1e-5f

typedef unsigned int   u32;
typedef unsigned long long u64;

// ============================================================================
// Cooperative mega-kernel. ALL phases grid-stride => correct for ANY grid size.
// Static 8 KB LDS reused across phases (transitions guarded by grid.sync(),
// which implies a block barrier).
// ============================================================================
__global__ __launch_bounds__(256) void mega(
    const float* __restrict__ X, const float* __restrict__ Hf,
    const float* __restrict__ Dv, const float* __restrict__ De,
    const float* __restrict__ W, const float* __restrict__ th1,
    const float* __restrict__ th2, const float* __restrict__ gm,
    const float* __restrict__ bt, float* __restrict__ out,
    u32* __restrict__ colcnt, float* __restrict__ bnp,
    u32* __restrict__ nzcnt, float* __restrict__ M2p, float* __restrict__ P2v,
    float* __restrict__ P, float* __restrict__ Mp,
    u32* __restrict__ nzlist, u32* __restrict__ colentry)
{
    __shared__ __align__(16) char smem_raw[8192];
    cg::grid_group gg = cg::this_grid();
    const int tid  = threadIdx.x;
    const int bid  = blockIdx.x;
    const int G    = gridDim.x;
    const int lane = tid & 63;
    const int wv   = tid >> 6;

    // ---- P0: zero colcnt (4096 u32) + bnp (1024 f32), contiguous 5120 words
    for (int idx = bid * 256 + tid; idx < 5120; idx += G * 256)
        colcnt[idx] = 0u;
    gg.sync();

    // ---- P1a: streaming scan of f32 H (134 MB). One wave per row.
    {
        u32* rowbuf = (u32*)smem_raw;       // [4][CAP] = 1536 B
        u64 ltmask = (lane == 63) ? 0x7FFFFFFFFFFFFFFFull : ((1ull << lane) - 1ull);
        for (int g = bid; g < N_V / 4; g += G) {
            int n = g * 4 + wv;
            const uint4* hrow4 = (const uint4*)(Hf + (size_t)n * N_E);
            uint4 q[16];
#pragma unroll
            for (int m = 0; m < 16; ++m)    // whole 16 KB row in flight
                q[m] = hrow4[m * 64 + lane];
            u32 cnt = 0;
#pragma unroll
            for (int m = 0; m < 16; ++m) {
                int ebase = (m * 64 + lane) * 4;
                u32 words[4] = { q[m].x, q[m].y, q[m].z, q[m].w };
#pragma unroll
                for (int j = 0; j < 4; ++j) {
                    bool has = (words[j] & 0x7FFFFFFFu) != 0u;
                    u64 bal = __ballot(has);
                    if (bal) {
                        if (has) {
                            u32 slot = cnt + (u32)__popcll(bal & ltmask);
                            if (slot < CAP) rowbuf[wv * CAP + slot] = (u32)(ebase + j);
                        }
                        cnt += (u32)__popcll(bal);
                    }
                }
            }
            if (cnt > CAP) cnt = CAP;
            if (lane == 0) nzcnt[n] = cnt;
            for (u32 i = lane; i < cnt; i += 64) {
                u32 e = rowbuf[wv * CAP + i];
                nzlist[(size_t)n * CAP + i] = e;
                u32 cs = atomicAdd(&colcnt[e], 1u);
                if (cs < CAPC) colentry[(size_t)e * CAPC + cs] = (u32)n;
            }
        }
    }

    // ---- P1b: proj P[n,h] = Dv[n] * sum_k X[n,k]*th1[k,h]
    {
        float (*Xs)[V_HID] = (float (*)[V_HID])smem_raw;   // 16 x 128 f32 = 8 KB
        for (int t = bid; t < N_V / 16; t += G) {
            __syncthreads();                // guard rowbuf/Xs + prev-iter reuse
            const float4* xr = (const float4*)(X + (size_t)t * 16 * V_HID);
            for (int i = tid; i < 512; i += 256) {
                float4 f = xr[i];
                int b = 4 * i;
                Xs[b >> 7][(b & 127) + 0] = f.x;
                Xs[b >> 7][(b & 127) + 1] = f.y;
                Xs[b >> 7][(b & 127) + 2] = f.z;
                Xs[b >> 7][(b & 127) + 3] = f.w;
            }
            __syncthreads();
            int r0 = wv * 4;
            float a0 = 0.f, a1 = 0.f, a2 = 0.f, a3 = 0.f;
#pragma unroll 8
            for (int k = 0; k < V_HID; ++k) {
                float tt = th1[k * H0_ + lane];   // coalesced 256B, L2-hot
                a0 += tt * Xs[r0 + 0][k];
                a1 += tt * Xs[r0 + 1][k];
                a2 += tt * Xs[r0 + 2][k];
                a3 += tt * Xs[r0 + 3][k];
            }
            int n0 = t * 16;
            P[(size_t)(n0 + r0 + 0) * H0_ + lane] = Dv[n0 + r0 + 0] * a0;
            P[(size_t)(n0 + r0 + 1) * H0_ + lane] = Dv[n0 + r0 + 1] * a1;
            P[(size_t)(n0 + r0 + 2) * H0_ + lane] = Dv[n0 + r0 + 2] * a2;
            P[(size_t)(n0 + r0 + 3) * H0_ + lane] = Dv[n0 + r0 + 3] * a3;
        }
    }
    gg.sync();

    // ---- P2: Mp[e,:] = W*De * sum_colnz P[n,:]
    for (int eg = bid; eg < N_E / 4; eg += G) {
        int e = eg * 4 + wv;
        u32 cw = colcnt[e];
        int cnt = cw < CAPC ? (int)cw : CAPC;
        const u32* ce = colentry + (size_t)e * CAPC;
        float acc0 = 0.f, acc1 = 0.f;
        int i = 0;
        for (; i + 8 <= cnt; i += 8) {
            uint4 a = *((const uint4*)(ce + i));
            uint4 b = *((const uint4*)(ce + i + 4));
            float p0 = P[(a.x & (N_V - 1)) * H0_ + lane];
            float p1 = P[(a.y & (N_V - 1)) * H0_ + lane];
            float p2 = P[(a.z & (N_V - 1)) * H0_ + lane];
            float p3 = P[(a.w & (N_V - 1)) * H0_ + lane];
            float p4 = P[(b.x & (N_V - 1)) * H0_ + lane];
            float p5 = P[(b.y & (N_V - 1)) * H0_ + lane];
            float p6 = P[(b.z & (N_V - 1)) * H0_ + lane];
            float p7 = P[(b.w & (N_V - 1)) * H0_ + lane];
            acc0 += (p0 + p1) + (p2 + p3);
            acc1 += (p4 + p5) + (p6 + p7);
        }
        for (; i < cnt; ++i)
            acc0 += P[(ce[i] & (N_V - 1)) * H0_ + lane];
        Mp[(size_t)e * H0_ + lane] = W[e] * De[e] * (acc0 + acc1);
    }
    gg.sync();

    // ---- P3: X1 = leaky_relu(Dv * sum_rownz Mp); BN partials. X1 aliases P.
    {
        float* ssum = (float*)smem_raw;     // [4][64]
        float* ssq  = ssum + 256;           // [4][64]
        for (int g = bid; g < N_V / 4; g += G) {
            int n = g * 4 + wv;
            const u32* lrow = nzlist + (size_t)n * CAP;
            u32 cw = nzcnt[n];
            int cnt = cw < CAP ? (int)cw : CAP;
            float acc0 = 0.f, acc1 = 0.f;
            int i = 0;
            for (; i + 8 <= cnt; i += 8) {
                uint4 a = *((const uint4*)(lrow + i));
                uint4 b = *((const uint4*)(lrow + i + 4));
                float p0 = Mp[(a.x & (N_E - 1)) * H0_ + lane];
                float p1 = Mp[(a.y & (N_E - 1)) * H0_ + lane];
                float p2 = Mp[(a.z & (N_E - 1)) * H0_ + lane];
                float p3 = Mp[(a.w & (N_E - 1)) * H0_ + lane];
                float p4 = Mp[(b.x & (N_E - 1)) * H0_ + lane];
                float p5 = Mp[(b.y & (N_E - 1)) * H0_ + lane];
                float p6 = Mp[(b.z & (N_E - 1)) * H0_ + lane];
                float p7 = Mp[(b.w & (N_E - 1)) * H0_ + lane];
                acc0 += (p0 + p1) + (p2 + p3);
                acc1 += (p4 + p5) + (p6 + p7);
            }
            for (; i < cnt; ++i)
                acc0 += Mp[(lrow[i] & (N_E - 1)) * H0_ + lane];
            float xb = Dv[n] * (acc0 + acc1);
            float x1 = xb > 0.f ? xb : 0.01f * xb;
            P[(size_t)n * H0_ + lane] = x1;   // X1 overwrites P (dead after P2)
            ssum[wv * 64 + lane] = x1;
            ssq [wv * 64 + lane] = x1 * x1;
            __syncthreads();
            if (wv == 0) {
                float a = ssum[0 * 64 + lane] + ssum[1 * 64 + lane] + ssum[2 * 64 + lane] + ssum[3 * 64 + lane];
                float b = ssq [0 * 64 + lane] + ssq [1 * 64 + lane] + ssq [2 * 64 + lane] + ssq [3 * 64 + lane];
                float* dst = bnp + (size_t)(g & 7) * 128;
                atomicAdd(&dst[lane], a);
                atomicAdd(&dst[64 + lane], b);
            }
            __syncthreads();
        }
    }
    gg.sync();

    // ---- P4: BN apply + theta2 dot; P2v[n] = Dv[n] * (BN(X1[n,:]).th2)
    {
        float sum = 0.f, sq = 0.f;          // loop-invariant: hoisted
#pragma unroll
        for (int p = 0; p < 8; ++p) { sum += bnp[p * 128 + lane]; sq += bnp[p * 128 + 64 + lane]; }
        float mu = sum * (1.f / N_V);
        float var = sq * (1.f / N_V) - mu * mu;
        float inv = rsqrtf(var + BN_EPS);
        float gm_l = gm[lane], bt_l = bt[lane], th2_l = th2[lane];
        for (int g = bid; g < N_V / 4; g += G) {
            int n = g * 4 + wv;
            float x = P[(size_t)n * H0_ + lane];
            float xn = (x - mu) * inv * gm_l + bt_l;   // exact round-0 form
            float t = xn * th2_l;
#pragma unroll
            for (int off = 32; off > 0; off >>= 1) t += __shfl_xor(t, off);
            if (lane == 0) P2v[n] = Dv[n] * t;
        }
    }
    gg.sync();

    // ---- P5: M2p[e] = W*De * sum_colnz P2v[n]
    for (int eg = bid; eg < N_E / 4; eg += G) {
        int e = eg * 4 + wv;
        u32 cw = colcnt[e];
        int cnt = cw < CAPC ? (int)cw : CAPC;
        const u32* ce = colentry + (size_t)e * CAPC;
        float s = 0.f;
        for (int i = lane; i < cnt; i += 64)
            s += P2v[ce[i] & (N_V - 1)];
#pragma unroll
        for (int off = 32; off > 0; off >>= 1) s += __shfl_xor(s, off);
        if (lane == 0) M2p[e] = W[e] * De[e] * s;
    }
    gg.sync();

    // ---- P6: out[n] = sigmoid(Dv[n] * sum_rownz M2p[e])
    for (int g = bid; g < N_V / 4; g += G) {
        int n = g * 4 + wv;
        u32 cw = nzcnt[n];
        int cnt = cw < CAP ? (int)cw : CAP;
        const u32* lrow = nzlist + (size_t)n * CAP;
        float s = 0.f;
        for (int i = lane; i < cnt; i += 64)
            s += M2p[lrow[i] & (N_E - 1)];
#pragma unroll
        for (int off = 32; off > 0; off >>= 1) s += __shfl_xor(s, off);
        if (lane == 0) {
            float xb = Dv[n] * s;
            out[n] = 1.f / (1.f + expf(-xb));
        }
    }
}

// ============================================================================
// Fallback: verbatim round-0 seven-kernel path (proven 257 us, absmax 0).
// ============================================================================
__global__ __launch_bounds__(256) void k1_proj(const float* __restrict__ X, const float* __restrict__ th1,
                                               const float* __restrict__ Dv, float* __restrict__ P,
                                               float* __restrict__ zero_region) {
    int tid = threadIdx.x;
    if (blockIdx.x < 20) zero_region[blockIdx.x * 256 + tid] = 0.f;
    __shared__ float Th[V_HID][H0_];
    __shared__ float Xs[16][V_HID];
    int n0 = blockIdx.x * 16;
    for (int i = tid; i < 2048; i += 256) {
        float4 f = ((const float4*)th1)[i];
        int b = 4 * i;
        Th[b >> 6][(b & 63) + 0] = f.x;
        Th[b >> 6][(b & 63) + 1] = f.y;
        Th[b >> 6][(b & 63) + 2] = f.z;
        Th[b >> 6][(b & 63) + 3] = f.w;
    }
    for (int i = tid; i < 512; i += 256) {
        float4 f = ((const float4*)(X + (size_t)n0 * V_HID))[i];
        int b = 4 * i;
        Xs[b >> 7][(b & 127) + 0] = f.x;
        Xs[b >> 7][(b & 127) + 1] = f.y;
        Xs[b >> 7][(b & 127) + 2] = f.z;
        Xs[b >> 7][(b & 127) + 3] = f.w;
    }
    __syncthreads();
    int h = tid & 63, g = tid >> 6;
    int r0 = g * 4;
    float a0 = 0.f, a1 = 0.f, a2 = 0.f, a3 = 0.f;
    for (int k = 0; k < V_HID; ++k) {
        float t = Th[k][h];
        a0 += t * Xs[r0 + 0][k];
        a1 += t * Xs[r0 + 1][k];
        a2 += t * Xs[r0 + 2][k];
        a3 += t * Xs[r0 + 3][k];
    }
    P[(size_t)(n0 + r0 + 0) * H0_ + h] = Dv[n0 + r0 + 0] * a0;
    P[(size_t)(n0 + r0 + 1) * H0_ + h] = Dv[n0 + r0 + 1] * a1;
    P[(size_t)(n0 + r0 + 2) * H0_ + h] = Dv[n0 + r0 + 2] * a2;
    P[(size_t)(n0 + r0 + 3) * H0_ + h] = Dv[n0 + r0 + 3] * a3;
}

__global__ __launch_bounds__(256) void k2a_scan(const float* __restrict__ Hf,
                                                u32* __restrict__ nzlist, u32* __restrict__ nzcnt,
                                                u32* __restrict__ colcnt, u32* __restrict__ colentry) {
    __shared__ u32 rowbuf[4][CAP];
    int tid = threadIdx.x;
    int lane = tid & 63, wv = tid >> 6;
    int n = blockIdx.x * 4 + wv;
    const uint4* hrow4 = (const uint4*)(Hf + (size_t)n * N_E);
    u64 ltmask = (lane == 63) ? 0x7FFFFFFFFFFFFFFFull : ((1ull << lane) - 1ull);
    uint4 q[16];
#pragma unroll
    for (int m = 0; m < 16; ++m)
        q[m] = hrow4[m * 64 + lane];
    u32 cnt = 0;
#pragma unroll
    for (int m = 0; m < 16; ++m) {
        int ebase = (m * 64 + lane) * 4;
        u32 words[4] = { q[m].x, q[m].y, q[m].z, q[m].w };
#pragma unroll
        for (int j = 0; j < 4; ++j) {
            bool has = (words[j] & 0x7FFFFFFFu) != 0u;
            u64 bal = __ballot(has);
            if (bal) {
                if (has) {
                    u32 slot = cnt + (u32)__popcll(bal & ltmask);
                    if (slot < CAP) rowbuf[wv][slot] = (u32)(ebase + j);
                }
                cnt += (u32)__popcll(bal);
            }
        }
    }
    if (cnt > CAP) cnt = CAP;
    if (lane == 0) nzcnt[n] = cnt;
    for (u32 i = lane; i < cnt; i += 64) {
        u32 e = rowbuf[wv][i];
        nzlist[(size_t)n * CAP + i] = e;
        u32 cs = atomicAdd(&colcnt[e], 1u);
        if (cs < CAPC) colentry[(size_t)e * CAPC + cs] = (u32)n;
    }
}

__global__ __launch_bounds__(256) void k2b_gather(const u32* __restrict__ colcnt, const u32* __restrict__ colentry,
                                                  const float* __restrict__ P, const float* __restrict__ W,
                                                  const float* __restrict__ De, float* __restrict__ Mp) {
    int lane = threadIdx.x & 63;
    int e = blockIdx.x * 4 + (threadIdx.x >> 6);
    u32 cw = colcnt[e];
    int cnt = cw < CAPC ? (int)cw : CAPC;
    const u32* ce = colentry + (size_t)e * CAPC;
    float acc0 = 0.f, acc1 = 0.f;
    int i = 0;
    for (; i + 8 <= cnt; i += 8) {
        uint4 a = *((const uint4*)(ce + i));
        uint4 b = *((const uint4*)(ce + i + 4));
        float p0 = P[(a.x & (N_V - 1)) * H0_ + lane];
        float p1 = P[(a.y & (N_V - 1)) * H0_ + lane];
        float p2 = P[(a.z & (N_V - 1)) * H0_ + lane];
        float p3 = P[(a.w & (N_V - 1)) * H0_ + lane];
        float p4 = P[(b.x & (N_V - 1)) * H0_ + lane];
        float p5 = P[(b.y & (N_V - 1)) * H0_ + lane];
        float p6 = P[(b.z & (N_V - 1)) * H0_ + lane];
        float p7 = P[(b.w & (N_V - 1)) * H0_ + lane];
        acc0 += (p0 + p1) + (p2 + p3);
        acc1 += (p4 + p5) + (p6 + p7);
    }
    for (; i < cnt; ++i)
        acc0 += P[(ce[i] & (N_V - 1)) * H0_ + lane];
    Mp[(size_t)e * H0_ + lane] = W[e] * De[e] * (acc0 + acc1);
}

__global__ __launch_bounds__(256) void k3_layer1(const u32* __restrict__ nzlist, const u32* __restrict__ nzcnt,
                                                 const float* __restrict__ Mp, const float* __restrict__ Dv,
                                                 float* __restrict__ X1, float* __restrict__ bnp) {
    int lane = threadIdx.x & 63;
    int wv = threadIdx.x >> 6;
    int n = blockIdx.x * 4 + wv;
    const u32* lrow = nzlist + (size_t)n * CAP;
    u32 cw = nzcnt[n];
    int cnt = cw < CAP ? (int)cw : CAP;
    float acc0 = 0.f, acc1 = 0.f;
    int i = 0;
    for (; i + 8 <= cnt; i += 8) {
        uint4 a = *((const uint4*)(lrow + i));
        uint4 b = *((const uint4*)(lrow + i + 4));
        float p0 = Mp[(a.x & (N_E - 1)) * H0_ + lane];
        float p1 = Mp[(a.y & (N_E - 1)) * H0_ + lane];
        float p2 = Mp[(a.z & (N_E - 1)) * H0_ + lane];
        float p3 = Mp[(a.w & (N_E - 1)) * H0_ + lane];
        float p4 = Mp[(b.x & (N_E - 1)) * H0_ + lane];
        float p5 = Mp[(b.y & (N_E - 1)) * H0_ + lane];
        float p6 = Mp[(b.z & (N_E - 1)) * H0_ + lane];
        float p7 = Mp[(b.w & (N_E - 1)) * H0_ + lane];
        acc0 += (p0 + p1) + (p2 + p3);
        acc1 += (p4 + p5) + (p6 + p7);
    }
    for (; i < cnt; ++i)
        acc0 += Mp[(lrow[i] & (N_E - 1)) * H0_ + lane];
    float xb = Dv[n] * (acc0 + acc1);
    float x1 = xb > 0.f ? xb : 0.01f * xb;
    X1[(size_t)n * H0_ + lane] = x1;
    __shared__ float ssum[4][H0_], ssq[4][H0_];
    ssum[wv][lane] = x1;
    ssq[wv][lane] = x1 * x1;
    __syncthreads();
    if (wv == 0) {
        float a = ssum[0][lane] + ssum[1][lane] + ssum[2][lane] + ssum[3][lane];
        float b = ssq[0][lane] + ssq[1][lane] + ssq[2][lane] + ssq[3][lane];
        float* dst = bnp + (size_t)(blockIdx.x & 7) * 128;
        atomicAdd(&dst[lane], a);
        atomicAdd(&dst[64 + lane], b);
    }
}

__global__ __launch_bounds__(256) void k5_bn_proj(const float* __restrict__ X1, const float* __restrict__ bnp,
                                                  const float* __restrict__ gamma, const float* __restrict__ beta,
                                                  const float* __restrict__ th2, const float* __restrict__ Dv,
                                                  float* __restrict__ P2) {
    int lane = threadIdx.x & 63;
    int n = (int)((blockIdx.x * 256 + threadIdx.x) >> 6);
    float sum = 0.f, sq = 0.f;
#pragma unroll
    for (int p = 0; p < 8; ++p) { sum += bnp[p * 128 + lane]; sq += bnp[p * 128 + 64 + lane]; }
    float mu = sum * (1.f / N_V);
    float var = sq * (1.f / N_V) - mu * mu;
    float inv = rsqrtf(var + BN_EPS);
    float x = X1[(size_t)n * H0_ + lane];
    float xn = (x - mu) * inv * gamma[lane] + beta[lane];
    float t = xn * th2[lane];
#pragma unroll
    for (int off = 32; off > 0; off >>= 1) t += __shfl_xor(t, off);
    if (lane == 0) P2[n] = Dv[n] * t;
}

__global__ __launch_bounds__(256) void k6_edge2(const u32* __restrict__ colcnt, const u32* __restrict__ colentry,
                                                const float* __restrict__ P2, const float* __restrict__ W,
                                                const float* __restrict__ De, float* __restrict__ M2p) {
    int lane = threadIdx.x & 63;
    int e = blockIdx.x * 4 + (threadIdx.x >> 6);
    u32 cw = colcnt[e];
    int cnt = cw < CAPC ? (int)cw : CAPC;
    const u32* ce = colentry + (size_t)e * CAPC;
    float s = 0.f;
    for (int i = lane; i < cnt; i += 64)
        s += P2[ce[i] & (N_V - 1)];
#pragma unroll
    for (int off = 32; off > 0; off >>= 1) s += __shfl_xor(s, off);
    if (lane == 0) M2p[e] = W[e] * De[e] * s;
}

__global__ __launch_bounds__(256) void k7_out(const u32* __restrict__ nzlist, const u32* __restrict__ nzcnt,
                                              const float* __restrict__ M2p, const float* __restrict__ Dv,
                                              float* __restrict__ out) {
    int lane = threadIdx.x & 63;
    int n = blockIdx.x * 4 + (threadIdx.x >> 6);
    u32 cw = nzcnt[n];
    int cnt = cw < CAP ? (int)cw : CAP;
    const u32* lrow = nzlist + (size_t)n * CAP;
    float s = 0.f;
    for (int i = lane; i < cnt; i += 64)
        s += M2p[lrow[i] & (N_E - 1)];
#pragma unroll
    for (int off = 32; off > 0; off >>= 1) s += __shfl_xor(s, off);
    if (lane == 0) {
        float xb = Dv[n] * s;
        out[n] = 1.f / (1.f + expf(-xb));
    }
}

// ============================================================================
static int g_mode = 0;      // 0 = undecided, 1 = cooperative, 2 = fallback
static int g_grid = 0;

extern "C" void kernel_launch(void* const* d_in, const int* in_sizes, int n_in,
                              void* d_out, int out_size, void* d_ws, size_t ws_size,
                              hipStream_t stream) {
    const float* X   = (const float*)d_in[0];
    const float* Dv  = (const float*)d_in[1];
    const float* De  = (const float*)d_in[2];
    const float* Hf  = (const float*)d_in[3];
    const float* W   = (const float*)d_in[4];
    const float* th1 = (const float*)d_in[5];
    const float* th2 = (const float*)d_in[6];
    const float* gm  = (const float*)d_in[7];
    const float* bt  = (const float*)d_in[8];
    float* out = (float*)d_out;

    char* ws = (char*)d_ws;
    u32*   colcnt   = (u32*)  (ws + 0);         // 4096*4   = 16384
    float* bnp      = (float*)(ws + 16384);     // 8*128*4  = 4096
    u32*   nzcnt    = (u32*)  (ws + 20480);     // -> 53248
    float* M2p      = (float*)(ws + 53248);     // -> 69632
    float* P2v      = (float*)(ws + 69632);     // -> 102400
    float* P        = (float*)(ws + 102400);    // 2 MB -> 2199552 (X1 aliases)
    float* Mp       = (float*)(ws + 2199552);   // 1 MB -> 3248128
    u32*   nzlist   = (u32*)  (ws + 3248128);   // 3 MB -> 6393856
    u32*   colentry = (u32*)  (ws + 6393856);   // 2.25 MB -> 8753152

    if (g_mode == 0) {
        // Host-only queries: safe under graph capture (no stream interaction).
        int dev = 0, coopAttr = 0, numCU = 0, nb = 0;
        hipGetDevice(&dev);
        hipDeviceGetAttribute(&coopAttr, hipDeviceAttributeCooperativeLaunch, dev);
        hipDeviceGetAttribute(&numCU, hipDeviceAttributeMultiprocessorCount, dev);
        hipError_t oe = hipOccupancyMaxActiveBlocksPerMultiprocessor(
            &nb, reinterpret_cast<const void*>(mega), 256, 0);
        if (coopAttr && oe == hipSuccess && nb >= 1 && numCU >= 1) {
            long cap = (long)nb * (long)numCU;
            g_grid = (int)(cap < 2048 ? cap : 2048);
            g_mode = 1;
        } else {
            g_mode = 2;
        }
    }

    if (g_mode == 1) {
        void* args[] = { (void*)&X, (void*)&Hf, (void*)&Dv, (void*)&De, (void*)&W,
                         (void*)&th1, (void*)&th2, (void*)&gm, (void*)&bt, (void*)&out,
                         (void*)&colcnt, (void*)&bnp, (void*)&nzcnt, (void*)&M2p, (void*)&P2v,
                         (void*)&P, (void*)&Mp, (void*)&nzlist, (void*)&colentry };
        hipError_t err = hipLaunchCooperativeKernel((const void*)mega, dim3(g_grid),
                                                    dim3(256), args, 0, stream);
        if (err == hipSuccess) return;
        g_mode = 2;   // latch fallback and fall through
    }

    // Fallback: proven round-0 path.
    k1_proj<<<N_V / 16, 256, 0, stream>>>(X, th1, Dv, P, (float*)ws);
    k2a_scan<<<N_V / 4, 256, 0, stream>>>(Hf, nzlist, nzcnt, colcnt, colentry);
    k2b_gather<<<N_E / 4, 256, 0, stream>>>(colcnt, colentry, P, W, De, Mp);
    k3_layer1<<<N_V / 4, 256, 0, stream>>>(nzlist, nzcnt, Mp, Dv, P /*X1*/, bnp);
    k5_bn_proj<<<N_V / 4, 256, 0, stream>>>(P /*X1*/, bnp, gm, bt, th2, Dv, P2v);
    k6_edge2<<<N_E / 4, 256, 0, stream>>>(colcnt, colentry, P2v, W, De, M2p);
    k7_out<<<N_V / 4, 256, 0, stream>>>(nzlist, nzcnt, M2p, Dv, out);
}

// Round 4
// 332.188 us; speedup vs baseline: 1.7940x; 1.7940x over previous
//
#include <hip/hip_runtime.h>
#include <math.h>

#define N_V   8192
#define N_E   4096
#define V_HID 128
#define H0_   64
#define CAP   96      // row nz capacity  (mean 41, sigma 6.4)
#define CAPC  144     // col nz capacity  (mean 82, sigma 9.0)
#define BN_EPS 1e-5f

typedef unsigned int   u32;
typedef unsigned long long u64;

// ============================================================================
// kA: merged scan + proj. Blocks 0..2047 stream-scan H (one wave per row);
// blocks 2048..2559 compute P = Dv * (X @ th1). Independent work, no sync.
// colcnt/bnp pre-zeroed by a hipMemsetAsync before this kernel.
// ============================================================================
__global__ __launch_bounds__(256) void kA_scan_proj(
    const float* __restrict__ Hf, const float* __restrict__ X,
    const float* __restrict__ th1, const float* __restrict__ Dv,
    float* __restrict__ P,
    u32* __restrict__ nzlist, u32* __restrict__ nzcnt,
    u32* __restrict__ colcnt, u32* __restrict__ colentry)
{
    __shared__ __align__(16) char sm[8192];
    const int tid  = threadIdx.x;
    const int bid  = blockIdx.x;
    const int lane = tid & 63;
    const int wv   = tid >> 6;

    if (bid < N_V / 4) {
        // ---- scan branch (identical to proven k2a) ----
        u32* rowbuf = (u32*)sm;             // [4][CAP]
        int n = bid * 4 + wv;
        const uint4* hrow4 = (const uint4*)(Hf + (size_t)n * N_E);
        u64 ltmask = (lane == 63) ? 0x7FFFFFFFFFFFFFFFull : ((1ull << lane) - 1ull);
        uint4 q[16];
#pragma unroll
        for (int m = 0; m < 16; ++m)        // whole 16 KB row in flight
            q[m] = hrow4[m * 64 + lane];
        u32 cnt = 0;
#pragma unroll
        for (int m = 0; m < 16; ++m) {
            int ebase = (m * 64 + lane) * 4;
            u32 words[4] = { q[m].x, q[m].y, q[m].z, q[m].w };
#pragma unroll
            for (int j = 0; j < 4; ++j) {
                bool has = (words[j] & 0x7FFFFFFFu) != 0u;
                u64 bal = __ballot(has);
                if (bal) {                  // wave-uniform skip
                    if (has) {
                        u32 slot = cnt + (u32)__popcll(bal & ltmask);
                        if (slot < CAP) rowbuf[wv * CAP + slot] = (u32)(ebase + j);
                    }
                    cnt += (u32)__popcll(bal);
                }
            }
        }
        if (cnt > CAP) cnt = CAP;
        if (lane == 0) nzcnt[n] = cnt;
        for (u32 i = lane; i < cnt; i += 64) {
            u32 e = rowbuf[wv * CAP + i];
            nzlist[(size_t)n * CAP + i] = e;
            u32 cs = atomicAdd(&colcnt[e], 1u);
            if (cs < CAPC) colentry[(size_t)e * CAPC + cs] = (u32)n;
        }
    } else {
        // ---- proj branch: 16 rows per block, th1 read from L2 ----
        float (*Xs)[V_HID] = (float (*)[V_HID])sm;   // 16 x 128 f32 = 8 KB
        int t  = bid - N_V / 4;             // [0, 512)
        int n0 = t * 16;
        const float4* xr = (const float4*)(X + (size_t)n0 * V_HID);
        for (int i = tid; i < 512; i += 256) {
            float4 f = xr[i];
            int b = 4 * i;
            Xs[b >> 7][(b & 127) + 0] = f.x;
            Xs[b >> 7][(b & 127) + 1] = f.y;
            Xs[b >> 7][(b & 127) + 2] = f.z;
            Xs[b >> 7][(b & 127) + 3] = f.w;
        }
        __syncthreads();
        int r0 = wv * 4;
        float a0 = 0.f, a1 = 0.f, a2 = 0.f, a3 = 0.f;
#pragma unroll 8
        for (int k = 0; k < V_HID; ++k) {
            float tt = th1[k * H0_ + lane];   // coalesced 256B, L2-hot
            a0 += tt * Xs[r0 + 0][k];
            a1 += tt * Xs[r0 + 1][k];
            a2 += tt * Xs[r0 + 2][k];
            a3 += tt * Xs[r0 + 3][k];
        }
        P[(size_t)(n0 + r0 + 0) * H0_ + lane] = Dv[n0 + r0 + 0] * a0;
        P[(size_t)(n0 + r0 + 1) * H0_ + lane] = Dv[n0 + r0 + 1] * a1;
        P[(size_t)(n0 + r0 + 2) * H0_ + lane] = Dv[n0 + r0 + 2] * a2;
        P[(size_t)(n0 + r0 + 3) * H0_ + lane] = Dv[n0 + r0 + 3] * a3;
    }
}

// K2b: Mp[e,:] = W[e]*De[e] * sum_colnz P[n,:]   (gather, 8 loads in flight)
__global__ __launch_bounds__(256) void k2b_gather(const u32* __restrict__ colcnt, const u32* __restrict__ colentry,
                                                  const float* __restrict__ P, const float* __restrict__ W,
                                                  const float* __restrict__ De, float* __restrict__ Mp) {
    int lane = threadIdx.x & 63;
    int e = blockIdx.x * 4 + (threadIdx.x >> 6);
    u32 cw = colcnt[e];
    int cnt = cw < CAPC ? (int)cw : CAPC;
    const u32* ce = colentry + (size_t)e * CAPC;
    float acc0 = 0.f, acc1 = 0.f;
    int i = 0;
    for (; i + 8 <= cnt; i += 8) {
        uint4 a = *((const uint4*)(ce + i));
        uint4 b = *((const uint4*)(ce + i + 4));
        float p0 = P[(a.x & (N_V - 1)) * H0_ + lane];
        float p1 = P[(a.y & (N_V - 1)) * H0_ + lane];
        float p2 = P[(a.z & (N_V - 1)) * H0_ + lane];
        float p3 = P[(a.w & (N_V - 1)) * H0_ + lane];
        float p4 = P[(b.x & (N_V - 1)) * H0_ + lane];
        float p5 = P[(b.y & (N_V - 1)) * H0_ + lane];
        float p6 = P[(b.z & (N_V - 1)) * H0_ + lane];
        float p7 = P[(b.w & (N_V - 1)) * H0_ + lane];
        acc0 += (p0 + p1) + (p2 + p3);
        acc1 += (p4 + p5) + (p6 + p7);
    }
    for (; i < cnt; ++i)
        acc0 += P[(ce[i] & (N_V - 1)) * H0_ + lane];
    Mp[(size_t)e * H0_ + lane] = W[e] * De[e] * (acc0 + acc1);
}

// K3: X1[n,:] = leaky_relu(Dv[n]*sum_rownz Mp[e,:]); BN partial sums
__global__ __launch_bounds__(256) void k3_layer1(const u32* __restrict__ nzlist, const u32* __restrict__ nzcnt,
                                                 const float* __restrict__ Mp, const float* __restrict__ Dv,
                                                 float* __restrict__ X1, float* __restrict__ bnp) {
    int lane = threadIdx.x & 63;
    int wv = threadIdx.x >> 6;
    int n = blockIdx.x * 4 + wv;
    const u32* lrow = nzlist + (size_t)n * CAP;
    u32 cw = nzcnt[n];
    int cnt = cw < CAP ? (int)cw : CAP;
    float acc0 = 0.f, acc1 = 0.f;
    int i = 0;
    for (; i + 8 <= cnt; i += 8) {
        uint4 a = *((const uint4*)(lrow + i));
        uint4 b = *((const uint4*)(lrow + i + 4));
        float p0 = Mp[(a.x & (N_E - 1)) * H0_ + lane];
        float p1 = Mp[(a.y & (N_E - 1)) * H0_ + lane];
        float p2 = Mp[(a.z & (N_E - 1)) * H0_ + lane];
        float p3 = Mp[(a.w & (N_E - 1)) * H0_ + lane];
        float p4 = Mp[(b.x & (N_E - 1)) * H0_ + lane];
        float p5 = Mp[(b.y & (N_E - 1)) * H0_ + lane];
        float p6 = Mp[(b.z & (N_E - 1)) * H0_ + lane];
        float p7 = Mp[(b.w & (N_E - 1)) * H0_ + lane];
        acc0 += (p0 + p1) + (p2 + p3);
        acc1 += (p4 + p5) + (p6 + p7);
    }
    for (; i < cnt; ++i)
        acc0 += Mp[(lrow[i] & (N_E - 1)) * H0_ + lane];
    float xb = Dv[n] * (acc0 + acc1);
    float x1 = xb > 0.f ? xb : 0.01f * xb;
    X1[(size_t)n * H0_ + lane] = x1;
    __shared__ float ssum[4][H0_], ssq[4][H0_];
    ssum[wv][lane] = x1;
    ssq[wv][lane] = x1 * x1;
    __syncthreads();
    if (wv == 0) {
        float a = ssum[0][lane] + ssum[1][lane] + ssum[2][lane] + ssum[3][lane];
        float b = ssq[0][lane] + ssq[1][lane] + ssq[2][lane] + ssq[3][lane];
        float* dst = bnp + (size_t)(blockIdx.x & 7) * 128;
        atomicAdd(&dst[lane], a);
        atomicAdd(&dst[64 + lane], b);
    }
}

// K5: BN apply + theta2 dot; P2v[n] = Dv[n] * (BN(X1[n,:]).th2)
// Blocks 0..32 also zero acc[8192]+done (8256 words) for k67.
__global__ __launch_bounds__(256) void k5_bn_proj(const float* __restrict__ X1, const float* __restrict__ bnp,
                                                  const float* __restrict__ gamma, const float* __restrict__ beta,
                                                  const float* __restrict__ th2, const float* __restrict__ Dv,
                                                  float* __restrict__ P2v, u32* __restrict__ acc_zero) {
    int lane = threadIdx.x & 63;
    {
        int idx = blockIdx.x * 256 + threadIdx.x;
        if (idx < 8256) acc_zero[idx] = 0u;     // acc (8192 f32) + done (+pad)
    }
    int n = (int)((blockIdx.x * 256 + threadIdx.x) >> 6);
    float sum = 0.f, sq = 0.f;
#pragma unroll
    for (int p = 0; p < 8; ++p) { sum += bnp[p * 128 + lane]; sq += bnp[p * 128 + 64 + lane]; }
    float mu = sum * (1.f / N_V);
    float var = sq * (1.f / N_V) - mu * mu;
    float inv = rsqrtf(var + BN_EPS);
    float x = X1[(size_t)n * H0_ + lane];
    float xn = (x - mu) * inv * gamma[lane] + beta[lane];
    float t = xn * th2[lane];
#pragma unroll
    for (int off = 32; off > 0; off >>= 1) t += __shfl_xor(t, off);
    if (lane == 0) P2v[n] = Dv[n] * t;
}

// K67: fused layer-2 edge gather + node scatter + last-block sigmoid.
//  per edge e: m2 = W*De * sum_colnz P2v[n]; scatter atomicAdd(acc[n], m2)
//  last finishing block: out[n] = sigmoid(Dv[n] * acc[n])
__global__ __launch_bounds__(256) void k67_out(const u32* __restrict__ colcnt, const u32* __restrict__ colentry,
                                               const float* __restrict__ P2v, const float* __restrict__ W,
                                               const float* __restrict__ De, const float* __restrict__ Dv,
                                               float* __restrict__ acc, u32* __restrict__ done,
                                               float* __restrict__ out) {
    int tid = threadIdx.x;
    int lane = tid & 63;
    int e = blockIdx.x * 4 + (tid >> 6);
    u32 cw = colcnt[e];
    int cnt = cw < CAPC ? (int)cw : CAPC;
    const u32* ce = colentry + (size_t)e * CAPC;
    float s = 0.f;
    for (int i = lane; i < cnt; i += 64)
        s += P2v[ce[i] & (N_V - 1)];
#pragma unroll
    for (int off = 32; off > 0; off >>= 1) s += __shfl_xor(s, off);
    float m2 = W[e] * De[e] * s;              // all lanes hold s after butterfly
    for (int i = lane; i < cnt; i += 64)
        atomicAdd(&acc[ce[i] & (N_V - 1)], m2);

    // completion protocol (no grid sync): per-thread release fence, block
    // barrier, one done-increment per block; last block drains the output.
    __threadfence();
    __syncthreads();
    __shared__ int amLast;
    if (tid == 0) {
        u32 old = atomicAdd(done, 1u);
        amLast = (old == (u32)(gridDim.x - 1));
    }
    __syncthreads();
    if (amLast) {
        __threadfence();                       // acquire side
        for (int n = tid; n < N_V; n += 256) {
            float a = __hip_atomic_load(&acc[n], __ATOMIC_RELAXED, __HIP_MEMORY_SCOPE_AGENT);
            float xb = Dv[n] * a;
            out[n] = 1.f / (1.f + expf(-xb));
        }
    }
}

extern "C" void kernel_launch(void* const* d_in, const int* in_sizes, int n_in,
                              void* d_out, int out_size, void* d_ws, size_t ws_size,
                              hipStream_t stream) {
    const float* X   = (const float*)d_in[0];
    const float* Dv  = (const float*)d_in[1];
    const float* De  = (const float*)d_in[2];
    const float* Hf  = (const float*)d_in[3];
    const float* W   = (const float*)d_in[4];
    const float* th1 = (const float*)d_in[5];
    const float* th2 = (const float*)d_in[6];
    const float* gm  = (const float*)d_in[7];
    const float* bt  = (const float*)d_in[8];
    float* out = (float*)d_out;

    char* ws = (char*)d_ws;
    u32*   colcnt   = (u32*)  (ws + 0);         // 4096*4 = 16384
    float* bnp      = (float*)(ws + 16384);     // 1024*4 -> 20480   [memset 0..20480]
    float* acc      = (float*)(ws + 20480);     // 8192*4 -> 53248   (zeroed by k5)
    u32*   done     = (u32*)  (ws + 53248);     // 4 (+pad) -> 53504 (zeroed by k5)
    u32*   nzcnt    = (u32*)  (ws + 53504);     // 8192*4 -> 86272
    float* P2v      = (float*)(ws + 86272);     // 8192*4 -> 119040
    float* P        = (float*)(ws + 131072);    // 8192*64*4 = 2 MB -> 2228224
    float* X1       = P;                        // reuse: P dead after k2b
    float* Mp       = (float*)(ws + 2228224);   // 4096*64*4 = 1 MB -> 3276800
    u32*   nzlist   = (u32*)  (ws + 3276800);   // 8192*96*4 = 3 MB -> 6422528
    u32*   colentry = (u32*)  (ws + 6422528);   // 4096*144*4 = 2.25 MB -> 8781824

    hipMemsetAsync(ws, 0, 20480, stream);       // colcnt + bnp
    kA_scan_proj<<<N_V / 4 + N_V / 16, 256, 0, stream>>>(Hf, X, th1, Dv, P,
                                                         nzlist, nzcnt, colcnt, colentry);
    k2b_gather<<<N_E / 4, 256, 0, stream>>>(colcnt, colentry, P, W, De, Mp);
    k3_layer1<<<N_V / 4, 256, 0, stream>>>(nzlist, nzcnt, Mp, Dv, X1, bnp);
    k5_bn_proj<<<N_V / 4, 256, 0, stream>>>(X1, bnp, gm, bt, th2, Dv, P2v, (u32*)acc);
    k67_out<<<N_E / 4, 256, 0, stream>>>(colcnt, colentry, P2v, W, De, Dv, acc, done, out);
}

// Round 5
// 253.222 us; speedup vs baseline: 2.3535x; 1.3118x over previous
//
#include <hip/hip_runtime.h>
#include <math.h>

#define N_V   8192
#define N_E   4096
#define V_HID 128
#define H0_   64
#define CAP   96      // row nz capacity  (mean 41, sigma 6.4)
#define CAPC  144     // col nz capacity  (mean 82, sigma 9.0)
#define BN_EPS 1e-5f

typedef unsigned int   u32;
typedef unsigned long long u64;

// ============================================================================
// kA: merged scan + proj. Blocks 0..2047 stream-scan H (one wave per row);
// blocks 2048..2559 compute P = Dv * (X @ th1). Independent work, no sync.
// colcnt/bnp pre-zeroed by a hipMemsetAsync before this kernel.
// ============================================================================
__global__ __launch_bounds__(256) void kA_scan_proj(
    const float* __restrict__ Hf, const float* __restrict__ X,
    const float* __restrict__ th1, const float* __restrict__ Dv,
    float* __restrict__ P,
    u32* __restrict__ nzlist, u32* __restrict__ nzcnt,
    u32* __restrict__ colcnt, u32* __restrict__ colentry)
{
    __shared__ __align__(16) char sm[8192];
    const int tid  = threadIdx.x;
    const int bid  = blockIdx.x;
    const int lane = tid & 63;
    const int wv   = tid >> 6;

    if (bid < N_V / 4) {
        // ---- scan branch (identical to proven k2a) ----
        u32* rowbuf = (u32*)sm;             // [4][CAP]
        int n = bid * 4 + wv;
        const uint4* hrow4 = (const uint4*)(Hf + (size_t)n * N_E);
        u64 ltmask = (lane == 63) ? 0x7FFFFFFFFFFFFFFFull : ((1ull << lane) - 1ull);
        uint4 q[16];
#pragma unroll
        for (int m = 0; m < 16; ++m)        // whole 16 KB row in flight
            q[m] = hrow4[m * 64 + lane];
        u32 cnt = 0;
#pragma unroll
        for (int m = 0; m < 16; ++m) {
            int ebase = (m * 64 + lane) * 4;
            u32 words[4] = { q[m].x, q[m].y, q[m].z, q[m].w };
#pragma unroll
            for (int j = 0; j < 4; ++j) {
                bool has = (words[j] & 0x7FFFFFFFu) != 0u;
                u64 bal = __ballot(has);
                if (bal) {                  // wave-uniform skip
                    if (has) {
                        u32 slot = cnt + (u32)__popcll(bal & ltmask);
                        if (slot < CAP) rowbuf[wv * CAP + slot] = (u32)(ebase + j);
                    }
                    cnt += (u32)__popcll(bal);
                }
            }
        }
        if (cnt > CAP) cnt = CAP;
        if (lane == 0) nzcnt[n] = cnt;
        for (u32 i = lane; i < cnt; i += 64) {
            u32 e = rowbuf[wv * CAP + i];
            nzlist[(size_t)n * CAP + i] = e;
            u32 cs = atomicAdd(&colcnt[e], 1u);
            if (cs < CAPC) colentry[(size_t)e * CAPC + cs] = (u32)n;
        }
    } else {
        // ---- proj branch: 16 rows per block, th1 read from L2 ----
        float (*Xs)[V_HID] = (float (*)[V_HID])sm;   // 16 x 128 f32 = 8 KB
        int t  = bid - N_V / 4;             // [0, 512)
        int n0 = t * 16;
        const float4* xr = (const float4*)(X + (size_t)n0 * V_HID);
        for (int i = tid; i < 512; i += 256) {
            float4 f = xr[i];
            int b = 4 * i;
            Xs[b >> 7][(b & 127) + 0] = f.x;
            Xs[b >> 7][(b & 127) + 1] = f.y;
            Xs[b >> 7][(b & 127) + 2] = f.z;
            Xs[b >> 7][(b & 127) + 3] = f.w;
        }
        __syncthreads();
        int r0 = wv * 4;
        float a0 = 0.f, a1 = 0.f, a2 = 0.f, a3 = 0.f;
#pragma unroll 8
        for (int k = 0; k < V_HID; ++k) {
            float tt = th1[k * H0_ + lane];   // coalesced 256B, L2-hot
            a0 += tt * Xs[r0 + 0][k];
            a1 += tt * Xs[r0 + 1][k];
            a2 += tt * Xs[r0 + 2][k];
            a3 += tt * Xs[r0 + 3][k];
        }
        P[(size_t)(n0 + r0 + 0) * H0_ + lane] = Dv[n0 + r0 + 0] * a0;
        P[(size_t)(n0 + r0 + 1) * H0_ + lane] = Dv[n0 + r0 + 1] * a1;
        P[(size_t)(n0 + r0 + 2) * H0_ + lane] = Dv[n0 + r0 + 2] * a2;
        P[(size_t)(n0 + r0 + 3) * H0_ + lane] = Dv[n0 + r0 + 3] * a3;
    }
}

// K2b: Mp[e,:] = W[e]*De[e] * sum_colnz P[n,:]   (gather, 8 loads in flight)
__global__ __launch_bounds__(256) void k2b_gather(const u32* __restrict__ colcnt, const u32* __restrict__ colentry,
                                                  const float* __restrict__ P, const float* __restrict__ W,
                                                  const float* __restrict__ De, float* __restrict__ Mp) {
    int lane = threadIdx.x & 63;
    int e = blockIdx.x * 4 + (threadIdx.x >> 6);
    u32 cw = colcnt[e];
    int cnt = cw < CAPC ? (int)cw : CAPC;
    const u32* ce = colentry + (size_t)e * CAPC;
    float acc0 = 0.f, acc1 = 0.f;
    int i = 0;
    for (; i + 8 <= cnt; i += 8) {
        uint4 a = *((const uint4*)(ce + i));
        uint4 b = *((const uint4*)(ce + i + 4));
        float p0 = P[(a.x & (N_V - 1)) * H0_ + lane];
        float p1 = P[(a.y & (N_V - 1)) * H0_ + lane];
        float p2 = P[(a.z & (N_V - 1)) * H0_ + lane];
        float p3 = P[(a.w & (N_V - 1)) * H0_ + lane];
        float p4 = P[(b.x & (N_V - 1)) * H0_ + lane];
        float p5 = P[(b.y & (N_V - 1)) * H0_ + lane];
        float p6 = P[(b.z & (N_V - 1)) * H0_ + lane];
        float p7 = P[(b.w & (N_V - 1)) * H0_ + lane];
        acc0 += (p0 + p1) + (p2 + p3);
        acc1 += (p4 + p5) + (p6 + p7);
    }
    for (; i < cnt; ++i)
        acc0 += P[(ce[i] & (N_V - 1)) * H0_ + lane];
    Mp[(size_t)e * H0_ + lane] = W[e] * De[e] * (acc0 + acc1);
}

// K3: X1[n,:] = leaky_relu(Dv[n]*sum_rownz Mp[e,:]); BN partial sums
__global__ __launch_bounds__(256) void k3_layer1(const u32* __restrict__ nzlist, const u32* __restrict__ nzcnt,
                                                 const float* __restrict__ Mp, const float* __restrict__ Dv,
                                                 float* __restrict__ X1, float* __restrict__ bnp) {
    int lane = threadIdx.x & 63;
    int wv = threadIdx.x >> 6;
    int n = blockIdx.x * 4 + wv;
    const u32* lrow = nzlist + (size_t)n * CAP;
    u32 cw = nzcnt[n];
    int cnt = cw < CAP ? (int)cw : CAP;
    float acc0 = 0.f, acc1 = 0.f;
    int i = 0;
    for (; i + 8 <= cnt; i += 8) {
        uint4 a = *((const uint4*)(lrow + i));
        uint4 b = *((const uint4*)(lrow + i + 4));
        float p0 = Mp[(a.x & (N_E - 1)) * H0_ + lane];
        float p1 = Mp[(a.y & (N_E - 1)) * H0_ + lane];
        float p2 = Mp[(a.z & (N_E - 1)) * H0_ + lane];
        float p3 = Mp[(a.w & (N_E - 1)) * H0_ + lane];
        float p4 = Mp[(b.x & (N_E - 1)) * H0_ + lane];
        float p5 = Mp[(b.y & (N_E - 1)) * H0_ + lane];
        float p6 = Mp[(b.z & (N_E - 1)) * H0_ + lane];
        float p7 = Mp[(b.w & (N_E - 1)) * H0_ + lane];
        acc0 += (p0 + p1) + (p2 + p3);
        acc1 += (p4 + p5) + (p6 + p7);
    }
    for (; i < cnt; ++i)
        acc0 += Mp[(lrow[i] & (N_E - 1)) * H0_ + lane];
    float xb = Dv[n] * (acc0 + acc1);
    float x1 = xb > 0.f ? xb : 0.01f * xb;
    X1[(size_t)n * H0_ + lane] = x1;
    __shared__ float ssum[4][H0_], ssq[4][H0_];
    ssum[wv][lane] = x1;
    ssq[wv][lane] = x1 * x1;
    __syncthreads();
    if (wv == 0) {
        float a = ssum[0][lane] + ssum[1][lane] + ssum[2][lane] + ssum[3][lane];
        float b = ssq[0][lane] + ssq[1][lane] + ssq[2][lane] + ssq[3][lane];
        float* dst = bnp + (size_t)(blockIdx.x & 7) * 128;
        atomicAdd(&dst[lane], a);
        atomicAdd(&dst[64 + lane], b);
    }
}

// K5: BN apply + theta2 dot; P2v[n] = Dv[n] * (BN(X1[n,:]).th2)
__global__ __launch_bounds__(256) void k5_bn_proj(const float* __restrict__ X1, const float* __restrict__ bnp,
                                                  const float* __restrict__ gamma, const float* __restrict__ beta,
                                                  const float* __restrict__ th2, const float* __restrict__ Dv,
                                                  float* __restrict__ P2v) {
    int lane = threadIdx.x & 63;
    int n = (int)((blockIdx.x * 256 + threadIdx.x) >> 6);
    float sum = 0.f, sq = 0.f;
#pragma unroll
    for (int p = 0; p < 8; ++p) { sum += bnp[p * 128 + lane]; sq += bnp[p * 128 + 64 + lane]; }
    float mu = sum * (1.f / N_V);
    float var = sq * (1.f / N_V) - mu * mu;
    float inv = rsqrtf(var + BN_EPS);
    float x = X1[(size_t)n * H0_ + lane];
    float xn = (x - mu) * inv * gamma[lane] + beta[lane];
    float t = xn * th2[lane];
#pragma unroll
    for (int off = 32; off > 0; off >>= 1) t += __shfl_xor(t, off);
    if (lane == 0) P2v[n] = Dv[n] * t;
}

// K6: M2p[e] = W[e]*De[e] * sum_colnz P2v[n]   (gather — proven fast)
__global__ __launch_bounds__(256) void k6_edge2(const u32* __restrict__ colcnt, const u32* __restrict__ colentry,
                                                const float* __restrict__ P2v, const float* __restrict__ W,
                                                const float* __restrict__ De, float* __restrict__ M2p) {
    int lane = threadIdx.x & 63;
    int e = blockIdx.x * 4 + (threadIdx.x >> 6);
    u32 cw = colcnt[e];
    int cnt = cw < CAPC ? (int)cw : CAPC;
    const u32* ce = colentry + (size_t)e * CAPC;
    float s = 0.f;
    for (int i = lane; i < cnt; i += 64)
        s += P2v[ce[i] & (N_V - 1)];
#pragma unroll
    for (int off = 32; off > 0; off >>= 1) s += __shfl_xor(s, off);
    if (lane == 0) M2p[e] = W[e] * De[e] * s;
}

// K7: out[n] = sigmoid(Dv[n] * sum_rownz M2p[e])   (gather — proven fast)
__global__ __launch_bounds__(256) void k7_out(const u32* __restrict__ nzlist, const u32* __restrict__ nzcnt,
                                              const float* __restrict__ M2p, const float* __restrict__ Dv,
                                              float* __restrict__ out) {
    int lane = threadIdx.x & 63;
    int n = blockIdx.x * 4 + (threadIdx.x >> 6);
    u32 cw = nzcnt[n];
    int cnt = cw < CAP ? (int)cw : CAP;
    const u32* lrow = nzlist + (size_t)n * CAP;
    float s = 0.f;
    for (int i = lane; i < cnt; i += 64)
        s += M2p[lrow[i] & (N_E - 1)];
#pragma unroll
    for (int off = 32; off > 0; off >>= 1) s += __shfl_xor(s, off);
    if (lane == 0) {
        float xb = Dv[n] * s;
        out[n] = 1.f / (1.f + expf(-xb));
    }
}

extern "C" void kernel_launch(void* const* d_in, const int* in_sizes, int n_in,
                              void* d_out, int out_size, void* d_ws, size_t ws_size,
                              hipStream_t stream) {
    const float* X   = (const float*)d_in[0];
    const float* Dv  = (const float*)d_in[1];
    const float* De  = (const float*)d_in[2];
    const float* Hf  = (const float*)d_in[3];
    const float* W   = (const float*)d_in[4];
    const float* th1 = (const float*)d_in[5];
    const float* th2 = (const float*)d_in[6];
    const float* gm  = (const float*)d_in[7];
    const float* bt  = (const float*)d_in[8];
    float* out = (float*)d_out;

    char* ws = (char*)d_ws;
    u32*   colcnt   = (u32*)  (ws + 0);         // 4096*4 = 16384
    float* bnp      = (float*)(ws + 16384);     // 1024*4 -> 20480   [memset 0..20480]
    u32*   nzcnt    = (u32*)  (ws + 20480);     // 8192*4 -> 53248
    float* M2p      = (float*)(ws + 53248);     // 4096*4 -> 69632
    float* P2v      = (float*)(ws + 69632);     // 8192*4 -> 102400
    float* P        = (float*)(ws + 131072);    // 8192*64*4 = 2 MB -> 2228224
    float* X1       = P;                        // reuse: P dead after k2b
    float* Mp       = (float*)(ws + 2228224);   // 4096*64*4 = 1 MB -> 3276800
    u32*   nzlist   = (u32*)  (ws + 3276800);   // 8192*96*4 = 3 MB -> 6422528
    u32*   colentry = (u32*)  (ws + 6422528);   // 4096*144*4 = 2.25 MB -> 8781824

    hipMemsetAsync(ws, 0, 20480, stream);       // colcnt + bnp
    kA_scan_proj<<<N_V / 4 + N_V / 16, 256, 0, stream>>>(Hf, X, th1, Dv, P,
                                                         nzlist, nzcnt, colcnt, colentry);
    k2b_gather<<<N_E / 4, 256, 0, stream>>>(colcnt, colentry, P, W, De, Mp);
    k3_layer1<<<N_V / 4, 256, 0, stream>>>(nzlist, nzcnt, Mp, Dv, X1, bnp);
    k5_bn_proj<<<N_V / 4, 256, 0, stream>>>(X1, bnp, gm, bt, th2, Dv, P2v);
    k6_edge2<<<N_E / 4, 256, 0, stream>>>(colcnt, colentry, P2v, W, De, M2p);
    k7_out<<<N_V / 4, 256, 0, stream>>>(nzlist, nzcnt, M2p, Dv, out);
}